// Round 7
// baseline (439.713 us; speedup 1.0000x reference)
//
#include <hip/hip_runtime.h>
#include <stdint.h>

#define BB 8
#define SS 2048
#define DD 1024
#define KREAL 204

typedef __attribute__((ext_vector_type(8))) short short8;
typedef __attribute__((ext_vector_type(4))) float floatx4;
typedef uint16_t u16;
typedef uint32_t u32;

__device__ __forceinline__ float bf2f(u16 u) {
    union { float f; u32 i; } c; c.i = ((u32)u) << 16; return c.f;
}
__device__ __forceinline__ u16 f2bf(float f) {
    union { float f; u32 i; } c; c.f = f;
    u32 i = c.i;
    u32 r = (i + 0x7FFFu + ((i >> 16) & 1u)) >> 16;
    return (u16)r;
}

#if defined(__has_builtin)
#if __has_builtin(__builtin_amdgcn_global_load_lds)
#define HAVE_GLL 1
#endif
#endif

__device__ __forceinline__ void gload16(const u16* g, u16* l) {
#ifdef HAVE_GLL
    __builtin_amdgcn_global_load_lds(
        (const __attribute__((address_space(1))) void*)(uintptr_t)g,
        (__attribute__((address_space(3))) void*)(u32)(uintptr_t)(void*)l,
        16, 0, 0);
#else
    *(uint4*)l = *(const uint4*)g;
#endif
}

#define VM_WAIT(N) asm volatile("s_waitcnt vmcnt(" #N ")" ::: "memory")
#define LGKM0()    asm volatile("s_waitcnt lgkmcnt(0)" ::: "memory")
#define S_BAR()    asm volatile("s_barrier" ::: "memory")

// ===========================================================================
// Legacy 64-wide-row swizzled staging (kept for k_gemm64 only).
// ===========================================================================
__device__ __forceinline__ void stage64(const u16* __restrict__ src, size_t ld,
                                        u16* lds, int tid) {
#pragma unroll
    for (int j = 0; j < 2; j++) {
        int flat = j * 256 + tid;
        int row = flat >> 3, slot = flat & 7;
        int kg = slot ^ (row & 7);
        gload16(src + (size_t)row * ld + kg * 8, lds + flat * 8);
    }
}
__device__ __forceinline__ short8 frag(const u16* lds, int row, int kslot) {
    return *(const short8*)&lds[(row << 6) + (((kslot ^ (row & 7)) & 7) << 3)];
}

// ===========================================================================
// 256x256 8-wave ring-5 GEMM core, HYBRID DUAL-PATH staging:
//   A half-tiles: global_load_lds DMA (proven protocol, rounds 1-5)
//   B half-tiles: global_load_dwordx4 -> VGPR -> ds_write_b128
// Rationale: all staging-schedule variants (4-slot, ring-5, panel-major)
// plateau at the SAME ~10 B/cyc/CU staging rate -> the lone DMA path is the
// suspected saturated resource; B traffic moves to the vector-return path.
//
// vmcnt protocol (4 vmcnt ops/point: 2 A-DMA + 2 B-loads; ds_writes are
// lgkmcnt). Wait proofs (exact, all NT in {4,16,32} incl. doload tails):
//   top VM_WAIT(12): 12 newest = {B(2t+5),A(2t+3),B(2t+4),A(2t+2),B(2t+3),
//     A(2t+1)} -> guarantees A(2t) + B(2t+2) and older. k0 phases safe.
//   mid VM_WAIT(12): 12 newest = {B(2t+6),A(2t+4),B(2t+5),A(2t+3),B(2t+4),
//     A(2t+2)} -> guarantees A(2t+1) (ROUND-6 BUG: this wait was missing ->
//     k1 phases could read slot sl1 before its DMA landed; fixed).
//     At t=NT-3 (B-loads not issued), newer-than-A(2t+1) = 12 -> 12 is the
//     unique constant safe for every iteration.
//   tails: t=NT-2 VM_WAIT(4) (4 newest = A(2NT-2),A(2NT-1)); t=NT-1 VM(0).
// LGKM0 before every s_barrier makes ds_writes visible across waves; rb
// dependencies (ds_write reading a B-load from 2 points prior) get
// compiler-inserted waits, which also drain older A-DMAs (in-order vmcnt).
// Slot layout and frag32 reads unchanged (SQ_LDS_BANK_CONFLICT==0, r1-5).
// ===========================================================================
__device__ __forceinline__ short8 frag32(const u16* plane, int row, int ks) {
    return *(const short8*)&plane[(row << 5) + (((ks ^ ((row >> 1) & 3)) & 3) << 3)];
}

template <int MT0, bool LOADB>
__device__ __forceinline__ void phase16(const u16* Apl, const u16* Bpl,
                                        int arow, int brow, int ln, int quad,
                                        short8 (&bv)[4], floatx4 (&acc)[8][4]) {
    short8 af[4];
#pragma unroll
    for (int i = 0; i < 4; i++) af[i] = frag32(Apl, arow + (MT0 + i) * 16 + ln, quad);
    if (LOADB) {
#pragma unroll
        for (int nt = 0; nt < 4; nt++) bv[nt] = frag32(Bpl, brow + nt * 16 + ln, quad);
    }
    __builtin_amdgcn_s_setprio(1);
#pragma unroll
    for (int i = 0; i < 4; i++)
#pragma unroll
        for (int nt = 0; nt < 4; nt++)
            acc[MT0 + i][nt] = __builtin_amdgcn_mfma_f32_16x16x32_bf16(
                af[i], bv[nt], acc[MT0 + i][nt], 0, 0, 0);
    __builtin_amdgcn_s_setprio(0);
}

// Shared ring body. POINTC(sl, h, par, hload, doload) stages half-tile h
// into slot sl (B from regs, A via DMA) and issues the B-load for hload.
#define RING5H_BODY(POINTC)                                                    \
    short8 bv[4];                                                              \
    int sl0 = 0, sl1 = 1;                                                      \
    _Pragma("unroll 2")                                                        \
    for (int t = 0; t < NT - 2; ++t) {                                         \
        const u16* Ap0 = Al + sl0 * 8192;  const u16* Bp0 = Bl + sl0 * 8192;   \
        const u16* Ap1 = Al + sl1 * 8192;  const u16* Bp1 = Bl + sl1 * 8192;   \
        const int st = sl0 ? sl0 - 1 : 4;                                      \
        VM_WAIT(12); LGKM0(); S_BAR();                                         \
        POINTC(st, 2 * t + 4, 0, 2 * t + 6, (2 * t + 6 < 2 * NT));             \
        phase16<0, true >(Ap0, Bp0, arow, brow, ln, quad, bv, acc);            \
        phase16<4, false>(Ap0, Bp0, arow, brow, ln, quad, bv, acc);            \
        VM_WAIT(12); LGKM0(); S_BAR();                                         \
        POINTC(sl0, 2 * t + 5, 1, 2 * t + 7, (2 * t + 7 < 2 * NT));            \
        phase16<0, true >(Ap1, Bp1, arow, brow, ln, quad, bv, acc);            \
        phase16<4, false>(Ap1, Bp1, arow, brow, ln, quad, bv, acc);            \
        sl0 += 2; if (sl0 >= 5) sl0 -= 5;                                      \
        sl1 += 2; if (sl1 >= 5) sl1 -= 5;                                      \
    }                                                                          \
    {   /* t = NT-2: nothing staged after -> no mid barrier needed */          \
        const u16* Ap0 = Al + sl0 * 8192;  const u16* Bp0 = Bl + sl0 * 8192;   \
        const u16* Ap1 = Al + sl1 * 8192;  const u16* Bp1 = Bl + sl1 * 8192;   \
        VM_WAIT(4); LGKM0(); S_BAR();                                          \
        phase16<0, true >(Ap0, Bp0, arow, brow, ln, quad, bv, acc);            \
        phase16<4, false>(Ap0, Bp0, arow, brow, ln, quad, bv, acc);            \
        phase16<0, true >(Ap1, Bp1, arow, brow, ln, quad, bv, acc);            \
        phase16<4, false>(Ap1, Bp1, arow, brow, ln, quad, bv, acc);            \
        sl0 += 2; if (sl0 >= 5) sl0 -= 5;                                      \
        sl1 += 2; if (sl1 >= 5) sl1 -= 5;                                      \
    }                                                                          \
    {   /* t = NT-1 */                                                         \
        const u16* Ap0 = Al + sl0 * 8192;  const u16* Bp0 = Bl + sl0 * 8192;   \
        const u16* Ap1 = Al + sl1 * 8192;  const u16* Bp1 = Bl + sl1 * 8192;   \
        VM_WAIT(0); LGKM0(); S_BAR();                                          \
        phase16<0, true >(Ap0, Bp0, arow, brow, ln, quad, bv, acc);            \
        phase16<4, false>(Ap0, Bp0, arow, brow, ln, quad, bv, acc);            \
        phase16<0, true >(Ap1, Bp1, arow, brow, ln, quad, bv, acc);            \
        phase16<4, false>(Ap1, Bp1, arow, brow, ln, quad, bv, acc);            \
    }

// Row-major operands (proj2, qk2).
template <int NT>
__device__ __forceinline__ void gemm_core5(
    const u16* __restrict__ Ag, size_t lda,
    const u16* __restrict__ Bg, size_t ldb,
    u16* lds, int tid, floatx4 (&acc)[8][4]) {
    static_assert(NT >= 3, "ring-5 core needs NT >= 3");
    const int lane = tid & 63, w = tid >> 6;
    const int arow = (w >> 2) * 128, brow = (w & 3) * 64;
    const int ln = lane & 15, quad = lane >> 4;
    const int srow = tid >> 2;
    const int kgp = (tid & 3) ^ ((srow >> 1) & 3);
    const u16* A0 = Ag + (size_t)srow * lda + kgp * 8;
    const u16* A1 = Ag + (size_t)(srow + 128) * lda + kgp * 8;
    const u16* B0 = Bg + (size_t)srow * ldb + kgp * 8;
    const u16* B1 = Bg + (size_t)(srow + 128) * ldb + kgp * 8;
    u16* Al = lds;
    u16* Bl = lds + 5 * 8192;

    uint4 rb[2][2];
#define LD_B(dst, h)                                                           \
    { dst[0] = *(const uint4*)(B0 + (size_t)(h) * 32);                         \
      dst[1] = *(const uint4*)(B1 + (size_t)(h) * 32); }
#define POINTR(sl, h, par, hload, doload)                                      \
    {                                                                          \
        *(uint4*)(Bl + (sl) * 8192 + tid * 8)        = rb[par][0];             \
        *(uint4*)(Bl + (sl) * 8192 + 4096 + tid * 8) = rb[par][1];             \
        gload16(A0 + (size_t)(h) * 32, Al + (sl) * 8192 + tid * 8);            \
        gload16(A1 + (size_t)(h) * 32, Al + (sl) * 8192 + 4096 + tid * 8);     \
        if (doload) LD_B(rb[par], hload);                                      \
    }

    LD_B(rb[0], 0); LD_B(rb[1], 1);
    POINTR(0, 0, 0, 2, true);
    POINTR(1, 1, 1, 3, true);
    POINTR(2, 2, 0, 4, true);
    POINTR(3, 3, 1, 5, true);

    RING5H_BODY(POINTR)
#undef POINTR
#undef LD_B
}

// Panel-major operands [k/32][row][32] (h2).
template <int NT>
__device__ __forceinline__ void gemm_core5p(
    const u16* __restrict__ Ag, size_t PSA,
    const u16* __restrict__ Bg, size_t PSB,
    u16* lds, int tid, floatx4 (&acc)[8][4]) {
    static_assert(NT >= 3, "ring-5 core needs NT >= 3");
    const int lane = tid & 63, w = tid >> 6;
    const int arow = (w >> 2) * 128, brow = (w & 3) * 64;
    const int ln = lane & 15, quad = lane >> 4;
    const int srow = tid >> 2;
    const int kgp = (tid & 3) ^ ((srow >> 1) & 3);
    const u16* A0 = Ag + (size_t)srow * 32 + kgp * 8;
    const u16* A1 = A0 + 4096;
    const u16* B0 = Bg + (size_t)srow * 32 + kgp * 8;
    const u16* B1 = B0 + 4096;
    u16* Al = lds;
    u16* Bl = lds + 5 * 8192;

    uint4 rb[2][2];
#define LD_B(dst, h)                                                           \
    { dst[0] = *(const uint4*)(B0 + (size_t)(h) * PSB);                        \
      dst[1] = *(const uint4*)(B1 + (size_t)(h) * PSB); }
#define POINTP(sl, h, par, hload, doload)                                      \
    {                                                                          \
        *(uint4*)(Bl + (sl) * 8192 + tid * 8)        = rb[par][0];             \
        *(uint4*)(Bl + (sl) * 8192 + 4096 + tid * 8) = rb[par][1];             \
        gload16(A0 + (size_t)(h) * PSA, Al + (sl) * 8192 + tid * 8);           \
        gload16(A1 + (size_t)(h) * PSA, Al + (sl) * 8192 + 4096 + tid * 8);    \
        if (doload) LD_B(rb[par], hload);                                      \
    }

    LD_B(rb[0], 0); LD_B(rb[1], 1);
    POINTP(0, 0, 0, 2, true);
    POINTP(1, 1, 1, 3, true);
    POINTP(2, 2, 0, 4, true);
    POINTP(3, 3, 1, 5, true);

    RING5H_BODY(POINTP)
#undef POINTP
#undef LD_B
}

// ===========================================================================
// Epilogue stores for the 256x256 tile (LDS bounce -> contiguous dwordx4).
// ===========================================================================
template <typename F>
__device__ __forceinline__ void store_rm256(u16* smem, u16* gbase, size_t ldc,
                                            int wm, int wn, int ln, int quad,
                                            int tid, F val) {
    for (int half = 0; half < 2; half++) {
        __syncthreads();
        if (wm == half) {
#pragma unroll
            for (int mt = 0; mt < 8; mt++)
#pragma unroll
                for (int nt = 0; nt < 4; nt++)
#pragma unroll
                    for (int r = 0; r < 4; r++)
                        smem[(mt * 16 + quad * 4 + r) * 264 + wn * 64 + nt * 16 + ln] =
                            val(mt, nt, r);
        }
        __syncthreads();
#pragma unroll
        for (int j = 0; j < 8; j++) {
            int flat = j * 512 + tid;
            int row = flat >> 5, c = flat & 31;
            *(uint4*)&gbase[(size_t)(half * 128 + row) * ldc + c * 8] =
                *(const uint4*)&smem[row * 264 + c * 8];
        }
    }
}

// Panel-major P store: P_p[t/32][s][32], panel stride 65536 u16.
template <typename F>
__device__ __forceinline__ void store_pm256(u16* smem, u16* pb, int s0, int t0,
                                            int wm, int wn, int ln, int quad,
                                            int tid, F val) {
    for (int half = 0; half < 2; half++) {
        __syncthreads();
        if (wm == half) {
#pragma unroll
            for (int mt = 0; mt < 8; mt++)
#pragma unroll
                for (int nt = 0; nt < 4; nt++)
#pragma unroll
                    for (int r = 0; r < 4; r++)
                        smem[(mt * 16 + quad * 4 + r) * 264 + wn * 64 + nt * 16 + ln] =
                            val(mt, nt, r);
        }
        __syncthreads();
#pragma unroll
        for (int j = 0; j < 8; j++) {
            int flat = j * 512 + tid;
            int row = flat >> 5, c = flat & 31;
            size_t panel = (size_t)(t0 >> 5) + (c >> 2);
            *(uint4*)&pb[panel * 65536 + (size_t)(s0 + half * 128 + row) * 32 + (c & 3) * 8] =
                *(const uint4*)&smem[row * 264 + c * 8];
        }
    }
}

// Panel-major transposed ut store: ut_p[t/32][d][32], panel stride 32768 u16.
template <typename F4>
__device__ __forceinline__ void store_tr256_pm(u16* smem, u16* utb, int n0,
                                               int s0loc, int wm, int wn,
                                               int ln, int quad, int tid, F4 val4) {
    for (int qr = 0; qr < 4; qr++) {
        __syncthreads();
        if (wn == qr) {
#pragma unroll
            for (int mt = 0; mt < 8; mt++)
#pragma unroll
                for (int nt = 0; nt < 4; nt++) {
                    ushort4 v = val4(mt, nt);
                    *(ushort4*)&smem[(nt * 16 + ln) * 264 + wm * 128 + mt * 16 + quad * 4] = v;
                }
        }
        __syncthreads();
#pragma unroll
        for (int j = 0; j < 4; j++) {
            int flat = j * 512 + tid;
            int c = flat >> 5, r8 = flat & 31;
            size_t panel = (size_t)(s0loc >> 5) + (r8 >> 2);
            *(uint4*)&utb[panel * 32768 + (size_t)(n0 + qr * 64 + c) * 32 + (r8 & 3) * 8] =
                *(const uint4*)&smem[c * 264 + r8 * 8];
        }
    }
}

// ---------------------------------------------------------------------------
// Merged prep (ONE launch, was cast + prep + memset):
//   z=0 Wq->Wqkt rows 0-255, z=1 Wk->Wqkt rows 256-511, z=2 Wv cast -> Wv16,
//   z=3 Wd->Wdt, z=4 bias prep + lg zero, z=5 x f32->bf16 cast.
// grid (32, 32, 6) x 256 threads.
// ---------------------------------------------------------------------------
__global__ __launch_bounds__(256) void k_prepall(
    const float* __restrict__ x, u16* __restrict__ x16,
    const float* __restrict__ Wq, const float* __restrict__ Wk,
    const float* __restrict__ Wv, const float* __restrict__ Wd,
    const float* __restrict__ bv, const float* __restrict__ bd,
    const float* __restrict__ bq, const float* __restrict__ bk,
    u16* __restrict__ Wqkt, u16* __restrict__ Wv16, u16* __restrict__ Wdt,
    float* __restrict__ bc, float* __restrict__ bqk, float* __restrict__ lg) {
    const int z = blockIdx.z;
    const int t = threadIdx.x;
    if (z == 5) {
        int id = blockIdx.y * 32 + blockIdx.x;
#pragma unroll
        for (int j = 0; j < 16; j++) {
            size_t i = ((size_t)j * 262144 + (size_t)id * 256 + t) * 4;
            float4 v = *(const float4*)&x[i];
            ushort4 p;
            p.x = f2bf(v.x); p.y = f2bf(v.y); p.z = f2bf(v.z); p.w = f2bf(v.w);
            *(ushort4*)&x16[i] = p;
        }
        return;
    }
    if (z == 4) {
        int id = blockIdx.y * 32 + blockIdx.x;
        if (id < 16) {
            __shared__ float red[4][64];
            int n = id * 64 + (t & 63);
            int dc = t >> 6;
            float s = 0.f;
            for (int d = dc * 256; d < dc * 256 + 256; d++)
                s += bv[d] * Wd[(size_t)d * 1024 + n];
            red[dc][t & 63] = s;
            __syncthreads();
            if (dc == 0) bc[n] = bd[n] + red[0][t & 63] + red[1][t & 63] + red[2][t & 63] + red[3][t & 63];
        } else if (id == 16) {
            for (int i = t; i < 512; i += 256) {
                float v = 0.f;
                if (i < KREAL) v = bq[i];
                else if (i >= 256 && i < 256 + KREAL) v = bk[i - 256];
                bqk[i] = v;
            }
        } else if (id < 25) {
            int seg = id - 17;
            for (int i = t; i < 2048; i += 256) lg[seg * 2048 + i] = 0.f;
        }
        return;
    }
    __shared__ u16 tile[32][33];
    int k0 = blockIdx.x * 32, n0 = blockIdx.y * 32;
    int tx = t & 31, ty = t >> 5;
    if (z == 2) {
        for (int i = ty; i < 32; i += 8) {
            size_t idx = (size_t)(k0 + i) * 1024 + n0 + tx;
            Wv16[idx] = f2bf(Wv[idx]);
        }
        return;
    }
    const float* W; u16* out; int N, Npad, rowoff;
    if (z == 0)      { W = Wq; out = Wqkt; N = KREAL; Npad = 256;  rowoff = 0;   }
    else if (z == 1) { W = Wk; out = Wqkt; N = KREAL; Npad = 256;  rowoff = 256; }
    else             { W = Wd; out = Wdt;  N = 1024;  Npad = 1024; rowoff = 0;   }
    if (n0 >= Npad) return;
    for (int i = ty; i < 32; i += 8) {
        int n = n0 + tx;
        tile[i][tx] = (n < N) ? f2bf(W[(size_t)(k0 + i) * N + n]) : (u16)0;
    }
    __syncthreads();
    for (int i = ty; i < 32; i += 8) {
        int n = n0 + i;
        if (n < Npad) out[(size_t)(rowoff + n) * 1024 + k0 + tx] = tile[tx][i];
    }
}

// ---------------------------------------------------------------------------
// Small GEMM (64x64 tiles): Wvdt[j][i] = sum_k Wv[i][k]*Wd[k][j].
// ---------------------------------------------------------------------------
__global__ __launch_bounds__(256) void k_gemm64(
    const u16* __restrict__ A, const u16* __restrict__ Bt,
    u16* __restrict__ C, int ldc) {
    __shared__ u16 As[64 * 64];
    __shared__ u16 Bs[64 * 64];
    const int tid = threadIdx.x;
    const int m0 = blockIdx.x * 64, n0 = blockIdx.y * 64;
    const int lane = tid & 63, w = tid >> 6;
    const int ln = lane & 15, quad = lane >> 4;

    floatx4 acc[4];
    floatx4 zero = {0.f, 0.f, 0.f, 0.f};
#pragma unroll
    for (int nt = 0; nt < 4; nt++) acc[nt] = zero;

    for (int kt = 0; kt < 16; kt++) {
        __syncthreads();
        stage64(A + (size_t)m0 * 1024 + kt * 64, 1024, As, tid);
        stage64(Bt + (size_t)n0 * 1024 + kt * 64, 1024, Bs, tid);
        __syncthreads();
#pragma unroll
        for (int kk = 0; kk < 2; kk++) {
            short8 av = frag(As, w * 16 + ln, kk * 4 + quad);
#pragma unroll
            for (int nt = 0; nt < 4; nt++) {
                short8 bvf = frag(Bs, nt * 16 + ln, kk * 4 + quad);
                acc[nt] = __builtin_amdgcn_mfma_f32_16x16x32_bf16(av, bvf, acc[nt], 0, 0, 0);
            }
        }
    }
    const int row0 = m0 + w * 16 + quad * 4;
#pragma unroll
    for (int nt = 0; nt < 4; nt++) {
        const int col = n0 + nt * 16 + ln;
        ushort4 pk;
        pk.x = f2bf(acc[nt][0]); pk.y = f2bf(acc[nt][1]);
        pk.z = f2bf(acc[nt][2]); pk.w = f2bf(acc[nt][3]);
        *reinterpret_cast<ushort4*>(&C[(size_t)col * ldc + row0]) = pk;
    }
}

// ---------------------------------------------------------------------------
// Merged projection, 256x256 hybrid ring-5 core, identity mapping.
// grid (64, 6), 512 threads, 160 KiB LDS.
// ---------------------------------------------------------------------------
__global__ __launch_bounds__(512, 2) void k_proj2(
    const u16* __restrict__ A, const u16* __restrict__ Wqkt,
    const u16* __restrict__ Wvdt, const float* __restrict__ bqk,
    u16* __restrict__ qkp, u16* __restrict__ ut) {
    __shared__ __align__(16) u16 lds[81920];
    const int tid = threadIdx.x;
    const int m0 = blockIdx.x * 256;
    const int by = blockIdx.y;
    const int lane = tid & 63, w = tid >> 6;
    const int wm = w >> 2, wn = w & 3;
    const int ln = lane & 15, quad = lane >> 4;

    floatx4 acc[8][4];
    floatx4 zero = {0.f, 0.f, 0.f, 0.f};
#pragma unroll
    for (int mt = 0; mt < 8; mt++)
#pragma unroll
        for (int nt = 0; nt < 4; nt++) acc[mt][nt] = zero;

    const u16* Ag = A + (size_t)m0 * 1024;
    const int n0 = (by < 2) ? by * 256 : (by - 2) * 256;
    const u16* Bg = (by < 2) ? (Wqkt + (size_t)n0 * 1024) : (Wvdt + (size_t)n0 * 1024);
    gemm_core5<16>(Ag, 1024, Bg, 1024, lds, tid, acc);

    if (by < 2) {
        float b4[4];
#pragma unroll
        for (int nt = 0; nt < 4; nt++) b4[nt] = bqk[n0 + wn * 64 + nt * 16 + ln];
        store_rm256(lds, qkp + (size_t)m0 * 512 + n0, 512, wm, wn, ln, quad, tid,
            [&](int mt, int nt, int r) -> u16 {
                return f2bf(acc[mt][nt][r] + b4[nt]);
            });
    } else {
        int b = m0 >> 11, s0loc = m0 & 2047;
        store_tr256_pm(lds, ut + (size_t)b * DD * SS, n0, s0loc, wm, wn, ln, quad, tid,
            [&](int mt, int nt) -> ushort4 {
                ushort4 pk;
                pk.x = f2bf(acc[mt][nt][0]); pk.y = f2bf(acc[mt][nt][1]);
                pk.z = f2bf(acc[mt][nt][2]); pk.w = f2bf(acc[mt][nt][3]);
                return pk;
            });
    }
}

// ---------------------------------------------------------------------------
// QK GEMM (all 8 batches): P = bf16(exp(q.k - 30)) written PANEL-MAJOR;
// row sums via atomics. grid (8, 8, 8), 512 threads, hybrid ring-5 core.
// ---------------------------------------------------------------------------
__global__ __launch_bounds__(512, 2) void k_qk2(
    const u16* __restrict__ qkp, u16* __restrict__ P, float* __restrict__ lg) {
    __shared__ __align__(16) u16 lds[81920];
    const int tid = threadIdx.x;
    const int s0 = blockIdx.x * 256, t0 = blockIdx.y * 256, bb = blockIdx.z;
    const int lane = tid & 63, w = tid >> 6;
    const int wm = w >> 2, wn = w & 3;
    const int ln = lane & 15, quad = lane >> 4;

    floatx4 acc[8][4];
    floatx4 zero = {0.f, 0.f, 0.f, 0.f};
#pragma unroll
    for (int mt = 0; mt < 8; mt++)
#pragma unroll
        for (int nt = 0; nt < 4; nt++) acc[mt][nt] = zero;

    gemm_core5<4>(qkp + ((size_t)bb * SS + s0) * 512, 512,
                  qkp + ((size_t)bb * SS + t0) * 512 + 256, 512, lds, tid, acc);

#pragma unroll
    for (int mt = 0; mt < 8; mt++)
#pragma unroll
        for (int nt = 0; nt < 4; nt++)
#pragma unroll
            for (int r = 0; r < 4; r++)
                acc[mt][nt][r] = __expf(acc[mt][nt][r] - 30.f);

#pragma unroll
    for (int mt = 0; mt < 8; mt++) {
#pragma unroll
        for (int r = 0; r < 4; r++) {
            float rs = acc[mt][0][r] + acc[mt][1][r] + acc[mt][2][r] + acc[mt][3][r];
            rs += __shfl_xor(rs, 1);
            rs += __shfl_xor(rs, 2);
            rs += __shfl_xor(rs, 4);
            rs += __shfl_xor(rs, 8);
            if (ln == 0)
                atomicAdd(&lg[(size_t)bb * SS + s0 + wm * 128 + mt * 16 + quad * 4 + r], rs);
        }
    }

    store_pm256(lds, P + (size_t)bb * SS * SS, s0, t0, wm, wn, ln, quad, tid,
        [&](int mt, int nt, int r) -> u16 { return f2bf(acc[mt][nt][r]); });
}

// ---------------------------------------------------------------------------
// Final GEMM (all 8 batches): out = (P.ut)/l + bc + x (f32 into d_out; LN
// in-place after). Hybrid ring-5 panel-major core, NT=32.
// grid (8, 4, 8), 512 threads.
// ---------------------------------------------------------------------------
__global__ __launch_bounds__(512, 2) void k_h2(
    const u16* __restrict__ P, const u16* __restrict__ ut,
    const float* __restrict__ lg, const float* __restrict__ bc,
    const float* __restrict__ xres, float* __restrict__ out) {
    __shared__ __align__(16) u16 lds[81920];
    const int tid = threadIdx.x;
    const int s0 = blockIdx.x * 256, d0 = blockIdx.y * 256, bb = blockIdx.z;
    const int lane = tid & 63, w = tid >> 6;
    const int wm = w >> 2;
    const int ln = lane & 15, quad = lane >> 4;

    floatx4 acc[8][4];
    floatx4 zero = {0.f, 0.f, 0.f, 0.f};
#pragma unroll
    for (int mt = 0; mt < 8; mt++)
#pragma unroll
        for (int nt = 0; nt < 4; nt++) acc[mt][nt] = zero;

    gemm_core5p<32>(P + (size_t)bb * SS * SS + (size_t)s0 * 32, (size_t)SS * 32,
                    ut + (size_t)bb * DD * SS + (size_t)d0 * 32, (size_t)DD * 32,
                    lds, tid, acc);

    float* smem = (float*)lds;
    float* outb = out + ((size_t)bb * SS + s0) * DD + d0;
    const float* xb = xres + ((size_t)bb * SS + s0) * DD + d0;
    const float* lgb = lg + (size_t)bb * SS + s0;
    const int wn = w & 3;
    for (int c4 = 0; c4 < 4; c4++) {
        __syncthreads();
        if (wm == (c4 >> 1)) {
#pragma unroll
            for (int i = 0; i < 4; i++)
#pragma unroll
                for (int nt = 0; nt < 4; nt++)
#pragma unroll
                    for (int r = 0; r < 4; r++)
                        smem[(i * 16 + quad * 4 + r) * 260 + wn * 64 + nt * 16 + ln] =
                            acc[(c4 & 1) * 4 + i][nt][r];
        }
        __syncthreads();
#pragma unroll
        for (int j = 0; j < 8; j++) {
            int flat = j * 512 + tid;
            int row = flat >> 6, q = flat & 63;
            float iv = 1.f / lgb[c4 * 64 + row];
            float4 a  = *(const float4*)&smem[row * 260 + q * 4];
            float4 b4 = *(const float4*)&bc[d0 + q * 4];
            float4 xr = *(const float4*)&xb[(size_t)(c4 * 64 + row) * DD + q * 4];
            float4 o;
            o.x = a.x * iv + b4.x + xr.x;
            o.y = a.y * iv + b4.y + xr.y;
            o.z = a.z * iv + b4.z + xr.z;
            o.w = a.w * iv + b4.w + xr.w;
            *(float4*)&outb[(size_t)(c4 * 64 + row) * DD + q * 4] = o;
        }
    }
}

// ---------------------------------------------------------------------------
// LayerNorm over last dim (1024), f32 IN-PLACE on d_out. Each block owns 4
// rows exclusively -> no cross-block hazard.
// ---------------------------------------------------------------------------
__global__ __launch_bounds__(256) void k_ln_f32(
    float* __restrict__ io, const float* __restrict__ gamma,
    const float* __restrict__ beta) {
    const int tid = threadIdx.x;
    const int lane = tid & 63, w = tid >> 6;
    const size_t row = (size_t)blockIdx.x * 4 + w;
    float* rp = io + row * DD;

    float v[16];
#pragma unroll
    for (int j = 0; j < 4; j++) {
        float4 t = *(const float4*)&rp[j * 256 + lane * 4];
        v[j * 4 + 0] = t.x; v[j * 4 + 1] = t.y; v[j * 4 + 2] = t.z; v[j * 4 + 3] = t.w;
    }
    float s = 0.f, sq = 0.f;
#pragma unroll
    for (int i = 0; i < 16; i++) { s += v[i]; sq += v[i] * v[i]; }
#pragma unroll
    for (int msk = 1; msk < 64; msk <<= 1) {
        s  += __shfl_xor(s,  msk, 64);
        sq += __shfl_xor(sq, msk, 64);
    }
    float mean = s * (1.f / 1024.f);
    float var  = sq * (1.f / 1024.f) - mean * mean;
    float rstd = rsqrtf(fmaxf(var, 0.f) + 1e-12f);
#pragma unroll
    for (int j = 0; j < 4; j++) {
        float4 g  = *(const float4*)&gamma[j * 256 + lane * 4];
        float4 bt = *(const float4*)&beta [j * 256 + lane * 4];
        float4 o;
        o.x = g.x * (v[j * 4 + 0] - mean) * rstd + bt.x;
        o.y = g.y * (v[j * 4 + 1] - mean) * rstd + bt.y;
        o.z = g.z * (v[j * 4 + 2] - mean) * rstd + bt.z;
        o.w = g.w * (v[j * 4 + 3] - mean) * rstd + bt.w;
        *(float4*)&rp[j * 256 + lane * 4] = o;
    }
}

// ---------------------------------------------------------------------------
extern "C" void kernel_launch(void* const* d_in, const int* in_sizes, int n_in,
                              void* d_out, int out_size, void* d_ws, size_t ws_size,
                              hipStream_t stream) {
    const float* x     = (const float*)d_in[0];
    const float* Wq    = (const float*)d_in[2];
    const float* bq    = (const float*)d_in[3];
    const float* Wk    = (const float*)d_in[4];
    const float* bk    = (const float*)d_in[5];
    const float* Wv    = (const float*)d_in[6];
    const float* bv    = (const float*)d_in[7];
    const float* Wd    = (const float*)d_in[8];
    const float* bd    = (const float*)d_in[9];
    const float* gamma = (const float*)d_in[10];
    const float* beta  = (const float*)d_in[11];
    float* out = (float*)d_out;

    // Workspace (round-5 layout; ut/P panel-major):
    //   [0, 16.78M)        qkp  [16384][512] bf16 (row-major)
    //   [16.78M, 50.33M)   ut   [8][64][1024][32] bf16 (panel-major)
    //   [50.33M, 117.44M)  P    [8][64][2048][32] bf16 (panel-major)
    //       aliases (dead before qk writes P):
    //         x16 @ 50.33M, Wv16 @ 83.89M, Wvdt @ 85.98M,
    //         Wdt @ 88.08M, Wqkt @ 90.18M
    //   [117.44M, ..)      lg (64K), bc (4K), bqk (2K)
    char* ws = (char*)d_ws;
    u16*   qkp  = (u16*)(ws + 0);
    u16*   ut   = (u16*)(ws + 16777216);
    u16*   P    = (u16*)(ws + 50331648);
    u16*   x16  = (u16*)(ws + 50331648);
    u16*   Wv16 = (u16*)(ws + 83886080);
    u16*   Wvdt = (u16*)(ws + 85983232);
    u16*   Wdt  = (u16*)(ws + 88080384);
    u16*   Wqkt = (u16*)(ws + 90177536);
    float* lg   = (float*)(ws + 117440512);
    float* bc   = (float*)(ws + 117506048);
    float* bqk  = (float*)(ws + 117510144);

    k_prepall<<<dim3(32, 32, 6), dim3(256), 0, stream>>>(
        x, x16, Wq, Wk, Wv, Wd, bv, bd, bq, bk, Wqkt, Wv16, Wdt, bc, bqk, lg);
    k_gemm64<<<dim3(16, 16), dim3(256), 0, stream>>>(Wv16, Wdt, Wvdt, 1024);

    k_proj2<<<dim3(64, 6), dim3(512), 0, stream>>>(x16, Wqkt, Wvdt, bqk, qkp, ut);

    k_qk2<<<dim3(8, 8, 8), dim3(512), 0, stream>>>(qkp, P, lg);
    k_h2 <<<dim3(8, 4, 8), dim3(512), 0, stream>>>(P, ut, lg, bc, x, out);

    k_ln_f32<<<dim3(4096), dim3(256), 0, stream>>>(out, gamma, beta);
}

// Round 8
// 353.836 us; speedup vs baseline: 1.2427x; 1.2427x over previous
//
#include <hip/hip_runtime.h>
#include <stdint.h>

#define BB 8
#define SS 2048
#define DD 1024
#define KREAL 204

typedef __attribute__((ext_vector_type(8))) short short8;
typedef __attribute__((ext_vector_type(4))) float floatx4;
typedef uint16_t u16;
typedef uint32_t u32;

__device__ __forceinline__ float bf2f(u16 u) {
    union { float f; u32 i; } c; c.i = ((u32)u) << 16; return c.f;
}
__device__ __forceinline__ u16 f2bf(float f) {
    union { float f; u32 i; } c; c.f = f;
    u32 i = c.i;
    u32 r = (i + 0x7FFFu + ((i >> 16) & 1u)) >> 16;
    return (u16)r;
}

#if defined(__has_builtin)
#if __has_builtin(__builtin_amdgcn_global_load_lds)
#define HAVE_GLL 1
#endif
#endif

__device__ __forceinline__ void gload16(const u16* g, u16* l) {
#ifdef HAVE_GLL
    __builtin_amdgcn_global_load_lds(
        (const __attribute__((address_space(1))) void*)(uintptr_t)g,
        (__attribute__((address_space(3))) void*)(u32)(uintptr_t)(void*)l,
        16, 0, 0);
#else
    *(uint4*)l = *(const uint4*)g;
#endif
}

#define VM_WAIT(N) asm volatile("s_waitcnt vmcnt(" #N ")" ::: "memory")
#define S_BAR()    asm volatile("s_barrier" ::: "memory")

// ===========================================================================
// Legacy 64-wide-row swizzled staging (kept for k_gemm64 only).
// ===========================================================================
__device__ __forceinline__ void stage64(const u16* __restrict__ src, size_t ld,
                                        u16* lds, int tid) {
#pragma unroll
    for (int j = 0; j < 2; j++) {
        int flat = j * 256 + tid;
        int row = flat >> 3, slot = flat & 7;
        int kg = slot ^ (row & 7);
        gload16(src + (size_t)row * ld + kg * 8, lds + flat * 8);
    }
}
__device__ __forceinline__ short8 frag(const u16* lds, int row, int kslot) {
    return *(const short8*)&lds[(row << 6) + (((kslot ^ (row & 7)) & 7) << 3)];
}

// ===========================================================================
// 256x256 8-wave GEMM core, RING-5 half-tile pipeline, PURE DMA staging
// (round-4 configuration — best verified: 358.4 µs total; the round-6/7
// hybrid B-path regressed k_h2 84->132 µs and is reverted).
// Full 160 KiB LDS: 5 A-slots + 5 B-slots of 16 KB. BK=64 as two K-half
// planes of 32. Staging via global_load_lds with pre-swizzled SOURCE
// (kg = slot ^ ((row>>1)&3)); frag reads apply the matching XOR -> max
// 2-way bank aliasing (free; SQ_LDS_BANK_CONFLICT == 0, rounds 1-5).
//
// Half-tile h = 2t+k lives in slot h%5; staged exactly 2 tiles ahead.
// Counted-vmcnt (4 loads per half-tile), never drains in the main loop:
//   tile t: VM(12); BAR; SH(2t+4); k0 phases; VM(12); BAR; SH(2t+5);
//   k1 phases.  Tails: t=NT-2 VM(12)/VM(8); t=NT-1 VM(4)/VM(0).
// Wait proof: at tile-t top, loads newer than S(2t) are exactly
// {S(2t+1),S(2t+2),S(2t+3)} = 12; mid, newer than S(2t+1) are 12.
// ===========================================================================
__device__ __forceinline__ short8 frag32(const u16* plane, int row, int ks) {
    return *(const short8*)&plane[(row << 5) + (((ks ^ ((row >> 1) & 3)) & 3) << 3)];
}

template <int MT0, bool LOADB>
__device__ __forceinline__ void phase16(const u16* Apl, const u16* Bpl,
                                        int arow, int brow, int ln, int quad,
                                        short8 (&bv)[4], floatx4 (&acc)[8][4]) {
    short8 af[4];
#pragma unroll
    for (int i = 0; i < 4; i++) af[i] = frag32(Apl, arow + (MT0 + i) * 16 + ln, quad);
    if (LOADB) {
#pragma unroll
        for (int nt = 0; nt < 4; nt++) bv[nt] = frag32(Bpl, brow + nt * 16 + ln, quad);
    }
    __builtin_amdgcn_s_setprio(1);
#pragma unroll
    for (int i = 0; i < 4; i++)
#pragma unroll
        for (int nt = 0; nt < 4; nt++)
            acc[MT0 + i][nt] = __builtin_amdgcn_mfma_f32_16x16x32_bf16(
                af[i], bv[nt], acc[MT0 + i][nt], 0, 0, 0);
    __builtin_amdgcn_s_setprio(0);
}

template <int NT>
__device__ __forceinline__ void gemm_core5(
    const u16* __restrict__ Ag, size_t lda,
    const u16* __restrict__ Bg, size_t ldb,
    u16* lds, int tid, floatx4 (&acc)[8][4]) {
    static_assert(NT >= 3, "ring-5 core needs NT >= 3");
    const int lane = tid & 63, w = tid >> 6;
    const int arow = (w >> 2) * 128, brow = (w & 3) * 64;
    const int ln = lane & 15, quad = lane >> 4;
    const int srow = tid >> 2;
    const int kgp = (tid & 3) ^ ((srow >> 1) & 3);
    const u16* A0 = Ag + (size_t)srow * lda + kgp * 8;
    const u16* A1 = Ag + (size_t)(srow + 128) * lda + kgp * 8;
    const u16* B0 = Bg + (size_t)srow * ldb + kgp * 8;
    const u16* B1 = Bg + (size_t)(srow + 128) * ldb + kgp * 8;
    u16* Al = lds;
    u16* Bl = lds + 5 * 8192;

    auto SH = [&](int sl, int h) {   // stage half-tile h -> slot sl (4 loads)
        size_t koff = (size_t)h * 32;
        gload16(A0 + koff, Al + sl * 8192 + tid * 8);
        gload16(A1 + koff, Al + sl * 8192 + 4096 + tid * 8);
        gload16(B0 + koff, Bl + sl * 8192 + tid * 8);
        gload16(B1 + koff, Bl + sl * 8192 + 4096 + tid * 8);
    };

    SH(0, 0); SH(1, 1); SH(2, 2); SH(3, 3);   // 16 loads

    short8 bv[4];
    int sl0 = 0, sl1 = 1;
#pragma unroll 2
    for (int t = 0; t < NT - 2; ++t) {
        const u16* Ap0 = Al + sl0 * 8192;  const u16* Bp0 = Bl + sl0 * 8192;
        const u16* Ap1 = Al + sl1 * 8192;  const u16* Bp1 = Bl + sl1 * 8192;
        const int st = sl0 ? sl0 - 1 : 4;          // (2t+4)%5
        VM_WAIT(12); S_BAR();
        SH(st, 2 * t + 4);
        phase16<0, true >(Ap0, Bp0, arow, brow, ln, quad, bv, acc);
        phase16<4, false>(Ap0, Bp0, arow, brow, ln, quad, bv, acc);
        VM_WAIT(12); S_BAR();
        SH(sl0, 2 * t + 5);                        // (2t+5)%5 == sl0
        phase16<0, true >(Ap1, Bp1, arow, brow, ln, quad, bv, acc);
        phase16<4, false>(Ap1, Bp1, arow, brow, ln, quad, bv, acc);
        sl0 += 2; if (sl0 >= 5) sl0 -= 5;
        sl1 += 2; if (sl1 >= 5) sl1 -= 5;
    }
    {   // t = NT-2: newer-than-needed = 12 (top) / 8 (mid)
        const u16* Ap0 = Al + sl0 * 8192;  const u16* Bp0 = Bl + sl0 * 8192;
        const u16* Ap1 = Al + sl1 * 8192;  const u16* Bp1 = Bl + sl1 * 8192;
        VM_WAIT(12); S_BAR();
        phase16<0, true >(Ap0, Bp0, arow, brow, ln, quad, bv, acc);
        phase16<4, false>(Ap0, Bp0, arow, brow, ln, quad, bv, acc);
        VM_WAIT(8); S_BAR();
        phase16<0, true >(Ap1, Bp1, arow, brow, ln, quad, bv, acc);
        phase16<4, false>(Ap1, Bp1, arow, brow, ln, quad, bv, acc);
        sl0 += 2; if (sl0 >= 5) sl0 -= 5;
        sl1 += 2; if (sl1 >= 5) sl1 -= 5;
    }
    {   // t = NT-1: newer = 4 (top) / 0 (mid)
        const u16* Ap0 = Al + sl0 * 8192;  const u16* Bp0 = Bl + sl0 * 8192;
        const u16* Ap1 = Al + sl1 * 8192;  const u16* Bp1 = Bl + sl1 * 8192;
        VM_WAIT(4); S_BAR();
        phase16<0, true >(Ap0, Bp0, arow, brow, ln, quad, bv, acc);
        phase16<4, false>(Ap0, Bp0, arow, brow, ln, quad, bv, acc);
        VM_WAIT(0); S_BAR();
        phase16<0, true >(Ap1, Bp1, arow, brow, ln, quad, bv, acc);
        phase16<4, false>(Ap1, Bp1, arow, brow, ln, quad, bv, acc);
    }
}

// ===========================================================================
// Epilogue stores for the 256x256 tile (LDS bounce -> contiguous dwordx4).
// ===========================================================================
template <typename F>
__device__ __forceinline__ void store_rm256(u16* smem, u16* gbase, size_t ldc,
                                            int wm, int wn, int ln, int quad,
                                            int tid, F val) {
    for (int half = 0; half < 2; half++) {
        __syncthreads();
        if (wm == half) {
#pragma unroll
            for (int mt = 0; mt < 8; mt++)
#pragma unroll
                for (int nt = 0; nt < 4; nt++)
#pragma unroll
                    for (int r = 0; r < 4; r++)
                        smem[(mt * 16 + quad * 4 + r) * 264 + wn * 64 + nt * 16 + ln] =
                            val(mt, nt, r);
        }
        __syncthreads();
#pragma unroll
        for (int j = 0; j < 8; j++) {
            int flat = j * 512 + tid;
            int row = flat >> 5, c = flat & 31;
            *(uint4*)&gbase[(size_t)(half * 128 + row) * ldc + c * 8] =
                *(const uint4*)&smem[row * 264 + c * 8];
        }
    }
}

template <typename F4>
__device__ __forceinline__ void store_tr256(u16* smem, u16* gbase, size_t ldg,
                                            int wm, int wn, int ln, int quad,
                                            int tid, F4 val4) {
    for (int qr = 0; qr < 4; qr++) {
        __syncthreads();
        if (wn == qr) {
#pragma unroll
            for (int mt = 0; mt < 8; mt++)
#pragma unroll
                for (int nt = 0; nt < 4; nt++) {
                    ushort4 v = val4(mt, nt);
                    *(ushort4*)&smem[(nt * 16 + ln) * 264 + wm * 128 + mt * 16 + quad * 4] = v;
                }
        }
        __syncthreads();
#pragma unroll
        for (int j = 0; j < 4; j++) {
            int flat = j * 512 + tid;
            int c = flat >> 5, r8 = flat & 31;
            *(uint4*)&gbase[(size_t)(qr * 64 + c) * ldg + r8 * 8] =
                *(const uint4*)&smem[c * 264 + r8 * 8];
        }
    }
}

// ---------------------------------------------------------------------------
// Merged prep (ONE launch, replaces cast + prep + memset — verified r7):
//   z=0 Wq->Wqkt rows 0-255, z=1 Wk->Wqkt rows 256-511, z=2 Wv cast -> Wv16,
//   z=3 Wd->Wdt, z=4 bias prep + lg zero, z=5 x f32->bf16 cast.
// grid (32, 32, 6) x 256 threads.
// ---------------------------------------------------------------------------
__global__ __launch_bounds__(256) void k_prepall(
    const float* __restrict__ x, u16* __restrict__ x16,
    const float* __restrict__ Wq, const float* __restrict__ Wk,
    const float* __restrict__ Wv, const float* __restrict__ Wd,
    const float* __restrict__ bv, const float* __restrict__ bd,
    const float* __restrict__ bq, const float* __restrict__ bk,
    u16* __restrict__ Wqkt, u16* __restrict__ Wv16, u16* __restrict__ Wdt,
    float* __restrict__ bc, float* __restrict__ bqk, float* __restrict__ lg) {
    const int z = blockIdx.z;
    const int t = threadIdx.x;
    if (z == 5) {
        int id = blockIdx.y * 32 + blockIdx.x;
#pragma unroll
        for (int j = 0; j < 16; j++) {
            size_t i = ((size_t)j * 262144 + (size_t)id * 256 + t) * 4;
            float4 v = *(const float4*)&x[i];
            ushort4 p;
            p.x = f2bf(v.x); p.y = f2bf(v.y); p.z = f2bf(v.z); p.w = f2bf(v.w);
            *(ushort4*)&x16[i] = p;
        }
        return;
    }
    if (z == 4) {
        int id = blockIdx.y * 32 + blockIdx.x;
        if (id < 16) {
            __shared__ float red[4][64];
            int n = id * 64 + (t & 63);
            int dc = t >> 6;
            float s = 0.f;
            for (int d = dc * 256; d < dc * 256 + 256; d++)
                s += bv[d] * Wd[(size_t)d * 1024 + n];
            red[dc][t & 63] = s;
            __syncthreads();
            if (dc == 0) bc[n] = bd[n] + red[0][t & 63] + red[1][t & 63] + red[2][t & 63] + red[3][t & 63];
        } else if (id == 16) {
            for (int i = t; i < 512; i += 256) {
                float v = 0.f;
                if (i < KREAL) v = bq[i];
                else if (i >= 256 && i < 256 + KREAL) v = bk[i - 256];
                bqk[i] = v;
            }
        } else if (id < 25) {
            int seg = id - 17;
            for (int i = t; i < 2048; i += 256) lg[seg * 2048 + i] = 0.f;
        }
        return;
    }
    __shared__ u16 tile[32][33];
    int k0 = blockIdx.x * 32, n0 = blockIdx.y * 32;
    int tx = t & 31, ty = t >> 5;
    if (z == 2) {
        for (int i = ty; i < 32; i += 8) {
            size_t idx = (size_t)(k0 + i) * 1024 + n0 + tx;
            Wv16[idx] = f2bf(Wv[idx]);
        }
        return;
    }
    const float* W; u16* out; int N, Npad, rowoff;
    if (z == 0)      { W = Wq; out = Wqkt; N = KREAL; Npad = 256;  rowoff = 0;   }
    else if (z == 1) { W = Wk; out = Wqkt; N = KREAL; Npad = 256;  rowoff = 256; }
    else             { W = Wd; out = Wdt;  N = 1024;  Npad = 1024; rowoff = 0;   }
    if (n0 >= Npad) return;
    for (int i = ty; i < 32; i += 8) {
        int n = n0 + tx;
        tile[i][tx] = (n < N) ? f2bf(W[(size_t)(k0 + i) * N + n]) : (u16)0;
    }
    __syncthreads();
    for (int i = ty; i < 32; i += 8) {
        int n = n0 + i;
        if (n < Npad) out[(size_t)(rowoff + n) * 1024 + k0 + tx] = tile[tx][i];
    }
}

// ---------------------------------------------------------------------------
// Small GEMM (64x64 tiles): Wvdt[j][i] = sum_k Wv[i][k]*Wd[k][j].
// ---------------------------------------------------------------------------
__global__ __launch_bounds__(256) void k_gemm64(
    const u16* __restrict__ A, const u16* __restrict__ Bt,
    u16* __restrict__ C, int ldc) {
    __shared__ u16 As[64 * 64];
    __shared__ u16 Bs[64 * 64];
    const int tid = threadIdx.x;
    const int m0 = blockIdx.x * 64, n0 = blockIdx.y * 64;
    const int lane = tid & 63, w = tid >> 6;
    const int ln = lane & 15, quad = lane >> 4;

    floatx4 acc[4];
    floatx4 zero = {0.f, 0.f, 0.f, 0.f};
#pragma unroll
    for (int nt = 0; nt < 4; nt++) acc[nt] = zero;

    for (int kt = 0; kt < 16; kt++) {
        __syncthreads();
        stage64(A + (size_t)m0 * 1024 + kt * 64, 1024, As, tid);
        stage64(Bt + (size_t)n0 * 1024 + kt * 64, 1024, Bs, tid);
        __syncthreads();
#pragma unroll
        for (int kk = 0; kk < 2; kk++) {
            short8 av = frag(As, w * 16 + ln, kk * 4 + quad);
#pragma unroll
            for (int nt = 0; nt < 4; nt++) {
                short8 bvf = frag(Bs, nt * 16 + ln, kk * 4 + quad);
                acc[nt] = __builtin_amdgcn_mfma_f32_16x16x32_bf16(av, bvf, acc[nt], 0, 0, 0);
            }
        }
    }
    const int row0 = m0 + w * 16 + quad * 4;
#pragma unroll
    for (int nt = 0; nt < 4; nt++) {
        const int col = n0 + nt * 16 + ln;
        ushort4 pk;
        pk.x = f2bf(acc[nt][0]); pk.y = f2bf(acc[nt][1]);
        pk.z = f2bf(acc[nt][2]); pk.w = f2bf(acc[nt][3]);
        *reinterpret_cast<ushort4*>(&C[(size_t)col * ldc + row0]) = pk;
    }
}

// ---------------------------------------------------------------------------
// Merged projection, 256x256 ring-5 core, identity mapping.
// grid (64, 6), 512 threads, 160 KiB LDS.
// ---------------------------------------------------------------------------
__global__ __launch_bounds__(512, 2) void k_proj2(
    const u16* __restrict__ A, const u16* __restrict__ Wqkt,
    const u16* __restrict__ Wvdt, const float* __restrict__ bqk,
    u16* __restrict__ qkp, u16* __restrict__ ut) {
    __shared__ __align__(16) u16 lds[81920];
    const int tid = threadIdx.x;
    const int m0 = blockIdx.x * 256;
    const int by = blockIdx.y;
    const int lane = tid & 63, w = tid >> 6;
    const int wm = w >> 2, wn = w & 3;
    const int ln = lane & 15, quad = lane >> 4;

    floatx4 acc[8][4];
    floatx4 zero = {0.f, 0.f, 0.f, 0.f};
#pragma unroll
    for (int mt = 0; mt < 8; mt++)
#pragma unroll
        for (int nt = 0; nt < 4; nt++) acc[mt][nt] = zero;

    const u16* Ag = A + (size_t)m0 * 1024;
    const int n0 = (by < 2) ? by * 256 : (by - 2) * 256;
    const u16* Bg = (by < 2) ? (Wqkt + (size_t)n0 * 1024) : (Wvdt + (size_t)n0 * 1024);
    gemm_core5<16>(Ag, 1024, Bg, 1024, lds, tid, acc);

    if (by < 2) {
        float b4[4];
#pragma unroll
        for (int nt = 0; nt < 4; nt++) b4[nt] = bqk[n0 + wn * 64 + nt * 16 + ln];
        store_rm256(lds, qkp + (size_t)m0 * 512 + n0, 512, wm, wn, ln, quad, tid,
            [&](int mt, int nt, int r) -> u16 {
                return f2bf(acc[mt][nt][r] + b4[nt]);
            });
    } else {
        int b = m0 >> 11, s0loc = m0 & 2047;
        store_tr256(lds, ut + ((size_t)b * DD + n0) * SS + s0loc, SS, wm, wn, ln, quad, tid,
            [&](int mt, int nt) -> ushort4 {
                ushort4 pk;
                pk.x = f2bf(acc[mt][nt][0]); pk.y = f2bf(acc[mt][nt][1]);
                pk.z = f2bf(acc[mt][nt][2]); pk.w = f2bf(acc[mt][nt][3]);
                return pk;
            });
    }
}

// ---------------------------------------------------------------------------
// QK GEMM (all 8 batches, one launch): P = bf16(exp(q.k - 30)); row sums via
// atomics. grid (8, 8, 8), 512 threads, identity mapping, ring-5 core.
// ---------------------------------------------------------------------------
__global__ __launch_bounds__(512, 2) void k_qk2(
    const u16* __restrict__ qkp, u16* __restrict__ P, float* __restrict__ lg) {
    __shared__ __align__(16) u16 lds[81920];
    const int tid = threadIdx.x;
    const int s0 = blockIdx.x * 256, t0 = blockIdx.y * 256, bb = blockIdx.z;
    const int lane = tid & 63, w = tid >> 6;
    const int wm = w >> 2, wn = w & 3;
    const int ln = lane & 15, quad = lane >> 4;

    floatx4 acc[8][4];
    floatx4 zero = {0.f, 0.f, 0.f, 0.f};
#pragma unroll
    for (int mt = 0; mt < 8; mt++)
#pragma unroll
        for (int nt = 0; nt < 4; nt++) acc[mt][nt] = zero;

    gemm_core5<4>(qkp + ((size_t)bb * SS + s0) * 512, 512,
                  qkp + ((size_t)bb * SS + t0) * 512 + 256, 512, lds, tid, acc);

#pragma unroll
    for (int mt = 0; mt < 8; mt++)
#pragma unroll
        for (int nt = 0; nt < 4; nt++)
#pragma unroll
            for (int r = 0; r < 4; r++)
                acc[mt][nt][r] = __expf(acc[mt][nt][r] - 30.f);

#pragma unroll
    for (int mt = 0; mt < 8; mt++) {
#pragma unroll
        for (int r = 0; r < 4; r++) {
            float rs = acc[mt][0][r] + acc[mt][1][r] + acc[mt][2][r] + acc[mt][3][r];
            rs += __shfl_xor(rs, 1);
            rs += __shfl_xor(rs, 2);
            rs += __shfl_xor(rs, 4);
            rs += __shfl_xor(rs, 8);
            if (ln == 0)
                atomicAdd(&lg[(size_t)bb * SS + s0 + wm * 128 + mt * 16 + quad * 4 + r], rs);
        }
    }

    store_rm256(lds, P + (size_t)bb * SS * SS + (size_t)s0 * SS + t0, SS,
                wm, wn, ln, quad, tid,
        [&](int mt, int nt, int r) -> u16 { return f2bf(acc[mt][nt][r]); });
}

// ---------------------------------------------------------------------------
// Final GEMM (all 8 batches, one launch): out = (P.ut)/l + bc + x  (f32,
// straight into d_out; LN runs in-place afterwards). Ring-5 core, NT=32.
// grid (8, 4, 8), 512 threads, identity mapping.
// ---------------------------------------------------------------------------
__global__ __launch_bounds__(512, 2) void k_h2(
    const u16* __restrict__ P, const u16* __restrict__ ut,
    const float* __restrict__ lg, const float* __restrict__ bc,
    const float* __restrict__ xres, float* __restrict__ out) {
    __shared__ __align__(16) u16 lds[81920];
    const int tid = threadIdx.x;
    const int s0 = blockIdx.x * 256, d0 = blockIdx.y * 256, bb = blockIdx.z;
    const int lane = tid & 63, w = tid >> 6;
    const int wm = w >> 2;
    const int ln = lane & 15, quad = lane >> 4;

    floatx4 acc[8][4];
    floatx4 zero = {0.f, 0.f, 0.f, 0.f};
#pragma unroll
    for (int mt = 0; mt < 8; mt++)
#pragma unroll
        for (int nt = 0; nt < 4; nt++) acc[mt][nt] = zero;

    gemm_core5<32>(P + ((size_t)bb * SS + s0) * SS, SS,
                   ut + ((size_t)bb * DD + d0) * SS, SS, lds, tid, acc);

    float* smem = (float*)lds;
    float* outb = out + ((size_t)bb * SS + s0) * DD + d0;
    const float* xb = xres + ((size_t)bb * SS + s0) * DD + d0;
    const float* lgb = lg + (size_t)bb * SS + s0;
    const int wn = w & 3;
    for (int c4 = 0; c4 < 4; c4++) {
        __syncthreads();
        if (wm == (c4 >> 1)) {
#pragma unroll
            for (int i = 0; i < 4; i++)
#pragma unroll
                for (int nt = 0; nt < 4; nt++)
#pragma unroll
                    for (int r = 0; r < 4; r++)
                        smem[(i * 16 + quad * 4 + r) * 260 + wn * 64 + nt * 16 + ln] =
                            acc[(c4 & 1) * 4 + i][nt][r];
        }
        __syncthreads();
#pragma unroll
        for (int j = 0; j < 8; j++) {
            int flat = j * 512 + tid;
            int row = flat >> 6, q = flat & 63;
            float iv = 1.f / lgb[c4 * 64 + row];
            float4 a  = *(const float4*)&smem[row * 260 + q * 4];
            float4 b4 = *(const float4*)&bc[d0 + q * 4];
            float4 xr = *(const float4*)&xb[(size_t)(c4 * 64 + row) * DD + q * 4];
            float4 o;
            o.x = a.x * iv + b4.x + xr.x;
            o.y = a.y * iv + b4.y + xr.y;
            o.z = a.z * iv + b4.z + xr.z;
            o.w = a.w * iv + b4.w + xr.w;
            *(float4*)&outb[(size_t)(c4 * 64 + row) * DD + q * 4] = o;
        }
    }
}

// ---------------------------------------------------------------------------
// LayerNorm over last dim (1024), f32 IN-PLACE on d_out. Each block owns 4
// rows exclusively -> no cross-block hazard.
// ---------------------------------------------------------------------------
__global__ __launch_bounds__(256) void k_ln_f32(
    float* __restrict__ io, const float* __restrict__ gamma,
    const float* __restrict__ beta) {
    const int tid = threadIdx.x;
    const int lane = tid & 63, w = tid >> 6;
    const size_t row = (size_t)blockIdx.x * 4 + w;
    float* rp = io + row * DD;

    float v[16];
#pragma unroll
    for (int j = 0; j < 4; j++) {
        float4 t = *(const float4*)&rp[j * 256 + lane * 4];
        v[j * 4 + 0] = t.x; v[j * 4 + 1] = t.y; v[j * 4 + 2] = t.z; v[j * 4 + 3] = t.w;
    }
    float s = 0.f, sq = 0.f;
#pragma unroll
    for (int i = 0; i < 16; i++) { s += v[i]; sq += v[i] * v[i]; }
#pragma unroll
    for (int msk = 1; msk < 64; msk <<= 1) {
        s  += __shfl_xor(s,  msk, 64);
        sq += __shfl_xor(sq, msk, 64);
    }
    float mean = s * (1.f / 1024.f);
    float var  = sq * (1.f / 1024.f) - mean * mean;
    float rstd = rsqrtf(fmaxf(var, 0.f) + 1e-12f);
#pragma unroll
    for (int j = 0; j < 4; j++) {
        float4 g  = *(const float4*)&gamma[j * 256 + lane * 4];
        float4 bt = *(const float4*)&beta [j * 256 + lane * 4];
        float4 o;
        o.x = g.x * (v[j * 4 + 0] - mean) * rstd + bt.x;
        o.y = g.y * (v[j * 4 + 1] - mean) * rstd + bt.y;
        o.z = g.z * (v[j * 4 + 2] - mean) * rstd + bt.z;
        o.w = g.w * (v[j * 4 + 3] - mean) * rstd + bt.w;
        *(float4*)&rp[j * 256 + lane * 4] = o;
    }
}

// ---------------------------------------------------------------------------
extern "C" void kernel_launch(void* const* d_in, const int* in_sizes, int n_in,
                              void* d_out, int out_size, void* d_ws, size_t ws_size,
                              hipStream_t stream) {
    const float* x     = (const float*)d_in[0];
    const float* Wq    = (const float*)d_in[2];
    const float* bq    = (const float*)d_in[3];
    const float* Wk    = (const float*)d_in[4];
    const float* bk    = (const float*)d_in[5];
    const float* Wv    = (const float*)d_in[6];
    const float* bv    = (const float*)d_in[7];
    const float* Wd    = (const float*)d_in[8];
    const float* bd    = (const float*)d_in[9];
    const float* gamma = (const float*)d_in[10];
    const float* beta  = (const float*)d_in[11];
    float* out = (float*)d_out;

    // Workspace (round-4 layout, all row-major):
    //   [0, 16.78M)        qkp  [16384][512] bf16
    //   [16.78M, 50.33M)   ut   [8][1024][2048] bf16
    //   [50.33M, 117.44M)  P    [8][2048][2048] bf16
    //       aliases (dead before qk writes P):
    //         x16 @ 50.33M, Wv16 @ 83.89M, Wvdt @ 85.98M,
    //         Wdt @ 88.08M, Wqkt @ 90.18M
    //   [117.44M, ..)      lg (64K), bc (4K), bqk (2K)
    char* ws = (char*)d_ws;
    u16*   qkp  = (u16*)(ws + 0);
    u16*   ut   = (u16*)(ws + 16777216);
    u16*   P    = (u16*)(ws + 50331648);
    u16*   x16  = (u16*)(ws + 50331648);
    u16*   Wv16 = (u16*)(ws + 83886080);
    u16*   Wvdt = (u16*)(ws + 85983232);
    u16*   Wdt  = (u16*)(ws + 88080384);
    u16*   Wqkt = (u16*)(ws + 90177536);
    float* lg   = (float*)(ws + 117440512);
    float* bc   = (float*)(ws + 117506048);
    float* bqk  = (float*)(ws + 117510144);

    k_prepall<<<dim3(32, 32, 6), dim3(256), 0, stream>>>(
        x, x16, Wq, Wk, Wv, Wd, bv, bd, bq, bk, Wqkt, Wv16, Wdt, bc, bqk, lg);
    k_gemm64<<<dim3(16, 16), dim3(256), 0, stream>>>(Wv16, Wdt, Wvdt, 1024);

    k_proj2<<<dim3(64, 6), dim3(512), 0, stream>>>(x16, Wqkt, Wvdt, bqk, qkp, ut);

    k_qk2<<<dim3(8, 8, 8), dim3(512), 0, stream>>>(qkp, P, lg);
    k_h2 <<<dim3(8, 4, 8), dim3(512), 0, stream>>>(P, ut, lg, bc, x, out);

    k_ln_f32<<<dim3(4096), dim3(256), 0, stream>>>(out, gamma, beta);
}